// Round 16
// baseline (238.995 us; speedup 1.0000x reference)
//
#include <hip/hip_runtime.h>
#include <math.h>

#define BB 32
#define NN 500
#define GG 500
#define HH 128
#define NHEADS 8
#define DD 16
#define KNB 16
#define PGT 8          // g-rows per pointer block
#define PTILES 63      // ceil(500/8)
#define NPAD 512       // embT row length (padded, zero-filled)
#define MCHUNK 25
#define MROWS 20

// ===========================================================================
// Combo kernel 1: independent prep work in one dispatch.
//   blocks [0,800)        : graph-mean partial sums (tid<128)
//   blocks [800,816)      : Wsum = Wq_first + Wq_last (tid<128)
//   blocks [816,4816)     : topk neighbors (256 thr, 4 rows/block)
//   blocks [4816,5840)    : emb -> embT transpose (LDS 32x64 tile)
// ===========================================================================
__global__ __launch_bounds__(256) void combo1_kernel(
    const float* __restrict__ emb, const float* __restrict__ Wqf,
    const float* __restrict__ Wql, const float* __restrict__ coords,
    const int* __restrict__ last_node, const float* __restrict__ mask,
    float* __restrict__ partial, float* __restrict__ Wsum,
    int* __restrict__ nbr, float* __restrict__ embT) {
  __shared__ float tt[32][65];
  __shared__ unsigned long long sel_keys[4][KNB];   // per-wave topk scratch
  int blk = blockIdx.x;
  int tid = threadIdx.x;

  if (blk < 800) {            // ---- mean partials ----
    if (tid < 128) {
      int b = blk / MCHUNK;
      int chunk = blk % MCHUNK;
      const float* eb = emb + ((size_t)b * NN + chunk * MROWS) * HH;
      float acc = 0.f;
#pragma unroll
      for (int n = 0; n < MROWS; ++n) acc += eb[n * HH + tid];
      partial[(size_t)blk * HH + tid] = acc;
    }
    return;
  }
  if (blk < 816) {            // ---- Wsum ----
    if (tid < 128) {
      int idx = (blk - 800) * 128 + tid;
      const float4* f4 = (const float4*)Wqf;
      const float4* l4 = (const float4*)Wql;
      float4* s4 = (float4*)Wsum;
      for (int i = idx; i < (HH * HH) / 4; i += 2048) {
        float4 a = f4[i], c = l4[i];
        s4[i] = make_float4(a.x + c.x, a.y + c.y, a.z + c.z, a.w + c.w);
      }
    }
    return;
  }
  if (blk < 4816) {           // ---- topk: bit-pattern binary search ----
    // Positive-float bits are order-monotone as uints: find the 16th-smallest
    // value via 31-step binary search (8 ballots + SALU popcounts per step,
    // no cross-lane shuffles). Selection = {u < V} + first (16-cnt_less) of
    // {u == V} in index order (== jax top_k stable tie-break). 16-key LDS
    // rank-sort restores exact ascending-(distance,index) reference order.
    int lane = tid & 63;
    int wid = tid >> 6;
    int row = (blk - 816) * 4 + wid;
    if (row >= BB * GG) return;      // never taken (4000*4 == 16000), uniform
    int b = row / GG;
    int last = last_node[row];
    const float* cb = coords + (size_t)b * NN * 2;
    float lx = cb[(size_t)last * 2 + 0];
    float ly = cb[(size_t)last * 2 + 1];
    const float* mrow = mask + (size_t)row * NN;
    unsigned u[8];
#pragma unroll
    for (int j = 0; j < 8; ++j) {
      int n = lane + j * 64;
      unsigned uv = 0x7FFFFFFFu;               // pad slots: above +inf
      if (n < NN) {
        float dx = lx - cb[n * 2];
        float dy = ly - cb[n * 2 + 1];
        float d = sqrtf(dx * dx + dy * dy);
        uv = __float_as_uint(d);               // d >= 0: bits are monotone
        if (mrow[n] == -INFINITY) uv = 0x7F800000u;   // +inf
      }
      u[j] = uv;
    }
    // smallest V with #{u <= V} >= 16  (V16 <= +inf always: 500 valid slots)
    unsigned lo = 0u, hi = 0x7F800000u;
    for (int it = 0; it < 31; ++it) {
      unsigned mid = (lo + hi) >> 1;
      int cnt = 0;
#pragma unroll
      for (int j = 0; j < 8; ++j)
        cnt += __popcll(__ballot(u[j] <= mid));
      if (cnt >= KNB) hi = mid; else lo = mid + 1;
    }
    unsigned V = hi;
    int cnt_less = 0;
#pragma unroll
    for (int j = 0; j < 8; ++j)
      cnt_less += __popcll(__ballot(u[j] < V));
    int extra = KNB - cnt_less;                // >= 1 by minimality of V
    // scatter the 16 selected keys (u:31 | n:9) into per-wave LDS
    unsigned long long below = (1ull << lane) - 1ull;
    unsigned long long* skey = &sel_keys[wid][0];
    int base_lt = 0, base_eq = 0;
#pragma unroll
    for (int j = 0; j < 8; ++j) {
      unsigned long long ltb = __ballot(u[j] < V);
      unsigned long long eqb = __ballot(u[j] == V);
      int n = lane + j * 64;
      if (u[j] < V) {
        int pos = base_lt + __popcll(ltb & below);
        skey[pos] = ((unsigned long long)u[j] << 9) | (unsigned)n;
      } else if (u[j] == V) {
        int erk = base_eq + __popcll(eqb & below);
        if (erk < extra)
          skey[cnt_less + erk] = ((unsigned long long)u[j] << 9) | (unsigned)n;
      }
      base_lt += __popcll(ltb);
      base_eq += __popcll(eqb);
    }
    // rank-sort 16 keys (DS ops are in-order within a wave; no barrier needed)
    if (lane < KNB) {
      unsigned long long mykey = skey[lane];
      int rank = 0;
#pragma unroll
      for (int k = 0; k < KNB; ++k)
        rank += (skey[k] < mykey) ? 1 : 0;
      nbr[(size_t)row * KNB + rank] = (int)(mykey & 511ull);
    }
    return;
  }
  // ---- transpose: emb(B,N,H) -> embT(B,H,NPAD), pad n>=500 with 0 ----
  {
    int blkt = blk - 4816;            // 0..1023
    int b = blkt >> 5;
    int t32 = blkt & 31;
    int h0 = (t32 >> 3) * 32;         // 4 h-tiles of 32
    int n0 = (t32 & 7) * 64;          // 8 n-tiles of 64
    int r = tid >> 2;                 // 0..63 (n within tile)
    int c = tid & 3;                  // h-octet 0..3
    int n = n0 + r;
    float4 f0 = make_float4(0.f, 0.f, 0.f, 0.f), f1 = f0;
    if (n < NN) {
      const float* src = emb + ((size_t)b * NN + n) * HH + h0 + c * 8;
      f0 = *(const float4*)(src);
      f1 = *(const float4*)(src + 4);
    }
    tt[c * 8 + 0][r] = f0.x; tt[c * 8 + 1][r] = f0.y;
    tt[c * 8 + 2][r] = f0.z; tt[c * 8 + 3][r] = f0.w;
    tt[c * 8 + 4][r] = f1.x; tt[c * 8 + 5][r] = f1.y;
    tt[c * 8 + 6][r] = f1.z; tt[c * 8 + 7][r] = f1.w;
    __syncthreads();
    int hr = tid >> 3;                // 0..31
    int nc = tid & 7;                 // 0..7 (n-octet)
    float* dst = embT + ((size_t)b * HH + h0 + hr) * NPAD + n0 + nc * 8;
    *(float4*)(dst)     = make_float4(tt[hr][nc*8+0], tt[hr][nc*8+1],
                                      tt[hr][nc*8+2], tt[hr][nc*8+3]);
    *(float4*)(dst + 4) = make_float4(tt[hr][nc*8+4], tt[hr][nc*8+5],
                                      tt[hr][nc*8+6], tt[hr][nc*8+7]);
  }
}

// ---------------------------------------------------------------------------
// Kernel 1b: reduce partials -> mean, project through Wqg -> qgraph (B,H)
// ---------------------------------------------------------------------------
__global__ __launch_bounds__(128) void qgraph_kernel(
    const float* __restrict__ partial, const float* __restrict__ Wqg,
    float* __restrict__ qgraph) {
  int b = blockIdx.x;
  int tid = threadIdx.x;
  __shared__ float meanv[HH];
  const float* p = partial + (size_t)b * MCHUNK * HH;
  float acc = 0.f;
#pragma unroll
  for (int c = 0; c < MCHUNK; ++c) acc += p[c * HH + tid];
  meanv[tid] = acc * (1.0f / NN);
  __syncthreads();
  const float4* wrow = (const float4*)(Wqg + (size_t)tid * HH);
  float s = 0.f;
#pragma unroll
  for (int k = 0; k < HH / 4; ++k) {
    float4 w = wrow[k];
    s += meanv[4 * k] * w.x + meanv[4 * k + 1] * w.y +
         meanv[4 * k + 2] * w.z + meanv[4 * k + 3] * w.w;
  }
  qgraph[b * HH + tid] = s;
}

// ---------------------------------------------------------------------------
// R2-style projection body: A and W both LDS-staged, 4 rows x 4 cols / thread.
// ---------------------------------------------------------------------------
__device__ __forceinline__ void proj_body(
    const float* __restrict__ A, const int* __restrict__ gather,
    const float* __restrict__ W, const float* __restrict__ bias,
    float* __restrict__ out, int mode, int blk,
    float (*As)[36], float (*Ws)[132]) {
  int tid = threadIdx.x;
  int row0 = blk * 32;

  float acc[4][4];
#pragma unroll
  for (int i = 0; i < 4; ++i)
#pragma unroll
    for (int j = 0; j < 4; ++j) acc[i][j] = 0.f;

  int cg = tid & 31; int c0 = cg * 4;
  int rg = tid >> 5; int r0 = rg * 4;

  int sr = tid >> 3;
  int skq = tid & 7;
  int grow = row0 + sr;
  int arow;
  if (gather) {
    int bofr = grow / GG;
    arow = bofr * NN + gather[grow];
  } else {
    arow = grow;
  }
  const float4* Arow4 = (const float4*)(A + (size_t)arow * HH);

  for (int ks = 0; ks < 4; ++ks) {
    int k0 = ks * 32;
    float4 a4 = Arow4[(k0 >> 2) + skq];
    As[skq * 4 + 0][sr] = a4.x;
    As[skq * 4 + 1][sr] = a4.y;
    As[skq * 4 + 2][sr] = a4.z;
    As[skq * 4 + 3][sr] = a4.w;
#pragma unroll
    for (int j = 0; j < 4; ++j) {
      int f = tid + j * 256;
      int o = f >> 3; int kq = f & 7;
      float4 w4 = *(const float4*)(W + (size_t)o * HH + k0 + kq * 4);
      Ws[kq * 4 + 0][o] = w4.x;
      Ws[kq * 4 + 1][o] = w4.y;
      Ws[kq * 4 + 2][o] = w4.z;
      Ws[kq * 4 + 3][o] = w4.w;
    }
    __syncthreads();
#pragma unroll
    for (int k = 0; k < 32; ++k) {
      float4 av = *(const float4*)&As[k][r0];
      float4 wv = *(const float4*)&Ws[k][c0];
      acc[0][0] += av.x*wv.x; acc[0][1] += av.x*wv.y;
      acc[0][2] += av.x*wv.z; acc[0][3] += av.x*wv.w;
      acc[1][0] += av.y*wv.x; acc[1][1] += av.y*wv.y;
      acc[1][2] += av.y*wv.z; acc[1][3] += av.y*wv.w;
      acc[2][0] += av.z*wv.x; acc[2][1] += av.z*wv.y;
      acc[2][2] += av.z*wv.z; acc[2][3] += av.z*wv.w;
      acc[3][0] += av.w*wv.x; acc[3][1] += av.w*wv.y;
      acc[3][2] += av.w*wv.z; acc[3][3] += av.w*wv.w;
    }
    __syncthreads();
  }

#pragma unroll
  for (int i = 0; i < 4; ++i) {
    int orow = row0 + r0 + i;
    float b0 = 0.f, b1 = 0.f, b2 = 0.f, b3 = 0.f;
    if (mode == 1) {
      int bofr = orow / GG;
      const float* qg = bias + bofr * HH + c0;
      b0 = qg[0]; b1 = qg[1]; b2 = qg[2]; b3 = qg[3];
    } else if (mode == 2) {
      b0 = bias[c0 + 0]; b1 = bias[c0 + 1]; b2 = bias[c0 + 2]; b3 = bias[c0 + 3];
    }
    float4 o4;
    o4.x = acc[i][0] + b0; o4.y = acc[i][1] + b1;
    o4.z = acc[i][2] + b2; o4.w = acc[i][3] + b3;
    *(float4*)(out + (size_t)orow * HH + c0) = o4;
  }
}

// seg 2: Qb=gather(emb)@Wsum + qgraph ; seg 3: FQ=AO@Wc + bc (after attn)
__global__ __launch_bounds__(256) void proj_kernel(
    const float* __restrict__ emb, const int* __restrict__ last_node,
    const float* __restrict__ Wsum, const float* __restrict__ qgraph,
    const float* __restrict__ Wc, const float* __restrict__ bc,
    const float* __restrict__ AO, float* __restrict__ Qb,
    float* __restrict__ FQ, int seg) {
  __shared__ float As[32][36];
  __shared__ float Ws[32][132];
  int blk = blockIdx.x % 500;
  if (seg == 2) proj_body(emb, last_node, Wsum, qgraph, Qb, 1, blk, As, Ws);
  else          proj_body(AO,  nullptr,   Wc,   bc,     FQ, 2, blk, As, Ws);
}

// ---------------------------------------------------------------------------
// Kernel 3b (R16): FUSED K+V projection. Segs 0 and 1 staged the SAME emb
// A-tile twice (emb = 8 MB read 2x, 2x A-staging + barriers). Fused: stage A
// once, Wk and Wv tiles side by side (LDS 4.6 + 2x16.9 = 38.4 KB -> 4
// blocks/CU), accumulate accK + accV (32 VGPR). Per k-step FMA:LDS-read
// improves 16:8 -> 32:12. Summation order per output unchanged ->
// bit-identical Kb/Vb.
// ---------------------------------------------------------------------------
__global__ __launch_bounds__(256) void projkv_kernel(
    const float* __restrict__ emb, const float* __restrict__ Wk,
    const float* __restrict__ Wv, float* __restrict__ Kb,
    float* __restrict__ Vb) {
  __shared__ float As[32][36];
  __shared__ float Wks[32][132];
  __shared__ float Wvs[32][132];
  int tid = threadIdx.x;
  int row0 = blockIdx.x * 32;

  float accK[4][4], accV[4][4];
#pragma unroll
  for (int i = 0; i < 4; ++i)
#pragma unroll
    for (int j = 0; j < 4; ++j) { accK[i][j] = 0.f; accV[i][j] = 0.f; }

  int cg = tid & 31; int c0 = cg * 4;
  int rg = tid >> 5; int r0 = rg * 4;
  int sr = tid >> 3;
  int skq = tid & 7;
  const float4* Arow4 = (const float4*)(emb + (size_t)(row0 + sr) * HH);

  for (int ks = 0; ks < 4; ++ks) {
    int k0 = ks * 32;
    float4 a4 = Arow4[(k0 >> 2) + skq];
    As[skq * 4 + 0][sr] = a4.x;
    As[skq * 4 + 1][sr] = a4.y;
    As[skq * 4 + 2][sr] = a4.z;
    As[skq * 4 + 3][sr] = a4.w;
#pragma unroll
    for (int j = 0; j < 4; ++j) {
      int f = tid + j * 256;
      int o = f >> 3; int kq = f & 7;
      float4 wk4 = *(const float4*)(Wk + (size_t)o * HH + k0 + kq * 4);
      Wks[kq * 4 + 0][o] = wk4.x;
      Wks[kq * 4 + 1][o] = wk4.y;
      Wks[kq * 4 + 2][o] = wk4.z;
      Wks[kq * 4 + 3][o] = wk4.w;
      float4 wv4 = *(const float4*)(Wv + (size_t)o * HH + k0 + kq * 4);
      Wvs[kq * 4 + 0][o] = wv4.x;
      Wvs[kq * 4 + 1][o] = wv4.y;
      Wvs[kq * 4 + 2][o] = wv4.z;
      Wvs[kq * 4 + 3][o] = wv4.w;
    }
    __syncthreads();
#pragma unroll
    for (int k = 0; k < 32; ++k) {
      float4 av = *(const float4*)&As[k][r0];
      float4 wk = *(const float4*)&Wks[k][c0];
      float4 wv = *(const float4*)&Wvs[k][c0];
      accK[0][0] += av.x*wk.x; accK[0][1] += av.x*wk.y;
      accK[0][2] += av.x*wk.z; accK[0][3] += av.x*wk.w;
      accK[1][0] += av.y*wk.x; accK[1][1] += av.y*wk.y;
      accK[1][2] += av.y*wk.z; accK[1][3] += av.y*wk.w;
      accK[2][0] += av.z*wk.x; accK[2][1] += av.z*wk.y;
      accK[2][2] += av.z*wk.z; accK[2][3] += av.z*wk.w;
      accK[3][0] += av.w*wk.x; accK[3][1] += av.w*wk.y;
      accK[3][2] += av.w*wk.z; accK[3][3] += av.w*wk.w;
      accV[0][0] += av.x*wv.x; accV[0][1] += av.x*wv.y;
      accV[0][2] += av.x*wv.z; accV[0][3] += av.x*wv.w;
      accV[1][0] += av.y*wv.x; accV[1][1] += av.y*wv.y;
      accV[1][2] += av.y*wv.z; accV[1][3] += av.y*wv.w;
      accV[2][0] += av.z*wv.x; accV[2][1] += av.z*wv.y;
      accV[2][2] += av.z*wv.z; accV[2][3] += av.z*wv.w;
      accV[3][0] += av.w*wv.x; accV[3][1] += av.w*wv.y;
      accV[3][2] += av.w*wv.z; accV[3][3] += av.w*wv.w;
    }
    __syncthreads();
  }

#pragma unroll
  for (int i = 0; i < 4; ++i) {
    int orow = row0 + r0 + i;
    *(float4*)(Kb + (size_t)orow * HH + c0) =
        make_float4(accK[i][0], accK[i][1], accK[i][2], accK[i][3]);
    *(float4*)(Vb + (size_t)orow * HH + c0) =
        make_float4(accV[i][0], accV[i][1], accV[i][2], accV[i][3]);
  }
}

// ---------------------------------------------------------------------------
// Kernel 4: sparse glimpse attention — R14 exact config (best measured).
// Direct-accumulate PV: weights broadcast via 640 B LDS, output accumulated
// straight from global V rows (bit-identical AO; no vacc buffer/barrier).
// R15's XCD swizzle on this kernel was neutral (16000 blocks give ample TLP
// to hide K/V L2 misses) -> reverted.
// ---------------------------------------------------------------------------
__global__ __launch_bounds__(128) void attn_kernel(
    const float* __restrict__ Q, const float* __restrict__ Kb,
    const float* __restrict__ Vb, const int* __restrict__ nbr,
    float* __restrict__ AO) {
  int row = blockIdx.x;
  int b = row / GG;
  int t = threadIdx.x;
  __shared__ float qs[HH];
  __shared__ int nb[KNB];
  __shared__ float aw[NHEADS * KNB];    // attention weights [h][i]
  qs[t] = Q[(size_t)row * HH + t];
  if (t < KNB) nb[t] = nbr[(size_t)row * KNB + t];
  __syncthreads();
  int h = t >> 4;
  int i = t & 15;
  size_t nrow = (size_t)b * NN + nb[i];
  const float4* kr = (const float4*)(Kb + nrow * HH + h * DD);
  const float4* q4 = (const float4*)(qs + h * DD);
  float4 k0 = kr[0], k1 = kr[1], k2 = kr[2], k3 = kr[3];
  float4 qa = q4[0], qb = q4[1], qc = q4[2], qd = q4[3];
  float s = k0.x*qa.x + k0.y*qa.y + k0.z*qa.z + k0.w*qa.w
          + k1.x*qb.x + k1.y*qb.y + k1.z*qb.z + k1.w*qb.w
          + k2.x*qc.x + k2.y*qc.y + k2.z*qc.z + k2.w*qc.w
          + k3.x*qd.x + k3.y*qd.y + k3.z*qd.z + k3.w*qd.w;
  s *= 0.25f;
  float m = s;
#pragma unroll
  for (int off = 8; off; off >>= 1) m = fmaxf(m, __shfl_xor(m, off, 64));
  float e = __expf(s - m);
  float sum = e;
#pragma unroll
  for (int off = 8; off; off >>= 1) sum += __shfl_xor(sum, off, 64);
  aw[h * KNB + i] = e / sum;
  __syncthreads();

  const float* awh = &aw[h * KNB];      // this thread's head weights
  const float* vb = Vb + (size_t)b * NN * HH + t;
  float o = 0.f;
#pragma unroll
  for (int k = 0; k < KNB; ++k)
    o += awh[k] * vb[(size_t)nb[k] * HH];
  AO[(size_t)row * HH + t] = o;
}

// ---------------------------------------------------------------------------
// Kernel 5: pointer scores — R11 config (best measured: 42-46 us, FETCH
// 28 MB, VGPR 52, zero spill). XCD-affine swizzle (embT L2-resident per
// XCD) + register double-buffer prefetch (covers ~200cy L2-hit latency with
// 512cy of FMA). Declared structurally floored in this decomposition (R12
// PGT=16 and R13 256-thr h-split both regressed via wave-supply / spill).
// tanh(x)*10 - 10 = -20/(exp(2x)+1); no max reduction needed.
// ---------------------------------------------------------------------------
__global__ __launch_bounds__(128) void pointer_kernel(
    const float* __restrict__ FQ, const float* __restrict__ embT,
    const float* __restrict__ mask, float* __restrict__ out) {
  int hb = blockIdx.x;                  // 0..2015
  int xcd = hb & 7;                     // presumed XCD (round-robin dispatch)
  int slot = hb >> 3;                   // 0..251 within this XCD
  int b = xcd * 4 + slot / PTILES;      // 4 b-slices per XCD (252 = 4*63)
  int g0 = (slot % PTILES) * PGT;
  int gc = min(PGT, GG - g0);
  int tid = threadIdx.x;

  const float* fq = FQ + (size_t)(b * GG + g0) * HH;   // block-uniform base
  const float4* et = (const float4*)(embT + (size_t)b * HH * NPAD);
  const float4* pe = et + tid;          // row h at pe[h*128]

  float4 acc[PGT];
#pragma unroll
  for (int g = 0; g < PGT; ++g) acc[g] = make_float4(0.f, 0.f, 0.f, 0.f);

  // prologue: rows 0..3 in flight
  float4 a0 = pe[0];
  float4 a1 = pe[128];
  float4 a2 = pe[256];
  float4 a3 = pe[384];
  pe += 512;

#define PTR_FMA_BLOCK(hh)                                          \
  do {                                                             \
    _Pragma("unroll")                                              \
    for (int g = 0; g < PGT; ++g) {                                \
      float4 w = *(const float4*)(fq + g * HH + (hh));             \
      acc[g].x = fmaf(a0.x, w.x, acc[g].x);                        \
      acc[g].x = fmaf(a1.x, w.y, acc[g].x);                        \
      acc[g].x = fmaf(a2.x, w.z, acc[g].x);                        \
      acc[g].x = fmaf(a3.x, w.w, acc[g].x);                        \
      acc[g].y = fmaf(a0.y, w.x, acc[g].y);                        \
      acc[g].y = fmaf(a1.y, w.y, acc[g].y);                        \
      acc[g].y = fmaf(a2.y, w.z, acc[g].y);                        \
      acc[g].y = fmaf(a3.y, w.w, acc[g].y);                        \
      acc[g].z = fmaf(a0.z, w.x, acc[g].z);                        \
      acc[g].z = fmaf(a1.z, w.y, acc[g].z);                        \
      acc[g].z = fmaf(a2.z, w.z, acc[g].z);                        \
      acc[g].z = fmaf(a3.z, w.w, acc[g].z);                        \
      acc[g].w = fmaf(a0.w, w.x, acc[g].w);                        \
      acc[g].w = fmaf(a1.w, w.y, acc[g].w);                        \
      acc[g].w = fmaf(a2.w, w.z, acc[g].w);                        \
      acc[g].w = fmaf(a3.w, w.w, acc[g].w);                        \
    }                                                              \
  } while (0)

#pragma unroll 2
  for (int h4 = 0; h4 < 31; ++h4) {
    // prefetch next 4 rows before this iteration's FMAs (256cy cover)
    float4 b0 = pe[0];
    float4 b1 = pe[128];
    float4 b2 = pe[256];
    float4 b3 = pe[384];
    pe += 512;
    PTR_FMA_BLOCK(h4 * 4);
    a0 = b0; a1 = b1; a2 = b2; a3 = b3;
  }
  PTR_FMA_BLOCK(124);                   // peeled final iteration
#undef PTR_FMA_BLOCK

  // epilogue: tanh-clip + mask + exp (in place), block-sum per g, normalize
  __shared__ float wred[2][PGT];
  __shared__ float tot[PGT];
  int lane = tid & 63;
  int w = tid >> 6;
  bool valid = (tid < 125);             // n = 4*tid < 500

#pragma unroll
  for (int g = 0; g < PGT; ++g) {
    float4 p = make_float4(0.f, 0.f, 0.f, 0.f);
    if (g < gc && valid) {
      const float* mrow = mask + (size_t)(b * GG + g0 + g) * NN;
      float4 m4 = *(const float4*)(mrow + 4 * tid);
      p.x = __expf(-20.f / (__expf(2.f * acc[g].x) + 1.f) + m4.x);
      p.y = __expf(-20.f / (__expf(2.f * acc[g].y) + 1.f) + m4.y);
      p.z = __expf(-20.f / (__expf(2.f * acc[g].z) + 1.f) + m4.z);
      p.w = __expf(-20.f / (__expf(2.f * acc[g].w) + 1.f) + m4.w);
    }
    acc[g] = p;
    float s = p.x + p.y + p.z + p.w;
#pragma unroll
    for (int off = 32; off; off >>= 1) s += __shfl_xor(s, off, 64);
    if (lane == 0) wred[w][g] = s;
  }
  __syncthreads();
  if (tid < PGT) tot[tid] = wred[0][tid] + wred[1][tid];
  __syncthreads();

#pragma unroll
  for (int g = 0; g < PGT; ++g) {
    if (g < gc && valid) {
      float inv = 1.f / tot[g];
      float4 p = acc[g];
      float4 o4 = make_float4(p.x * inv, p.y * inv, p.z * inv, p.w * inv);
      *(float4*)(out + (size_t)(b * GG + g0 + g) * NN + 4 * tid) = o4;
    }
  }
}

// ---------------------------------------------------------------------------
extern "C" void kernel_launch(void* const* d_in, const int* in_sizes, int n_in,
                              void* d_out, int out_size, void* d_ws,
                              size_t ws_size, hipStream_t stream) {
  const float* coords    = (const float*)d_in[0];
  const float* emb       = (const float*)d_in[1];
  const int*   last_node = (const int*)d_in[2];
  const float* mask      = (const float*)d_in[3];
  const float* Wqg       = (const float*)d_in[4];
  const float* Wqf       = (const float*)d_in[5];
  const float* Wql       = (const float*)d_in[6];
  const float* Wk        = (const float*)d_in[7];
  const float* Wv        = (const float*)d_in[8];
  const float* Wc        = (const float*)d_in[9];
  const float* bc        = (const float*)d_in[10];

  float* wsf    = (float*)d_ws;
  float* Wsum   = wsf;                            // 16 K floats
  float* qgraph = Wsum + HH * HH;                 // 4 K
  float* Kb     = qgraph + BB * HH;               // 2.048 M
  float* Vb     = Kb + (size_t)BB * NN * HH;      // 2.048 M
  float* Qb     = Vb + (size_t)BB * NN * HH;      // 2.048 M (reused for FQ)
  float* AO     = Qb + (size_t)BB * GG * HH;      // 2.048 M
  int*   nbr    = (int*)(AO + (size_t)BB * GG * HH);      // 256 K ints
  float* partial = (float*)(nbr + (size_t)BB * GG * KNB); // 102 K
  float* embT   = partial + (size_t)BB * MCHUNK * HH;     // 2.097 M

  float* outp   = (float*)d_out;

  combo1_kernel<<<5840, 256, 0, stream>>>(emb, Wqf, Wql, coords, last_node,
                                          mask, partial, Wsum, nbr, embT);
  qgraph_kernel<<<BB, 128, 0, stream>>>(partial, Wqg, qgraph);
  projkv_kernel<<<500, 256, 0, stream>>>(emb, Wk, Wv, Kb, Vb);
  proj_kernel<<<500, 256, 0, stream>>>(emb, last_node, Wsum, qgraph,
                                       Wc, bc, AO, Qb, Qb, 2);
  attn_kernel<<<BB * GG, 128, 0, stream>>>(Qb, Kb, Vb, nbr, AO);
  proj_kernel<<<500, 256, 0, stream>>>(emb, last_node, Wsum, qgraph,
                                       Wc, bc, AO, Qb, Qb, 3);
  pointer_kernel<<<BB * PTILES, 128, 0, stream>>>(Qb, embT, mask, outp);
}

// Round 17
// 229.201 us; speedup vs baseline: 1.0427x; 1.0427x over previous
//
#include <hip/hip_runtime.h>
#include <math.h>

#define BB 32
#define NN 500
#define GG 500
#define HH 128
#define NHEADS 8
#define DD 16
#define KNB 16
#define PGT 8          // g-rows per pointer block
#define PTILES 63      // ceil(500/8)
#define NPAD 512       // embT row length (padded, zero-filled)
#define MCHUNK 25
#define MROWS 20

// ===========================================================================
// Combo kernel 1: independent prep work in one dispatch.
//   blocks [0,800)        : graph-mean partial sums (tid<128)
//   blocks [800,816)      : Wsum = Wq_first + Wq_last (tid<128)
//   blocks [816,4816)     : topk neighbors (256 thr, 4 rows/block)
//   blocks [4816,5840)    : emb -> embT transpose (LDS 32x64 tile)
// ===========================================================================
__global__ __launch_bounds__(256) void combo1_kernel(
    const float* __restrict__ emb, const float* __restrict__ Wqf,
    const float* __restrict__ Wql, const float* __restrict__ coords,
    const int* __restrict__ last_node, const float* __restrict__ mask,
    float* __restrict__ partial, float* __restrict__ Wsum,
    int* __restrict__ nbr, float* __restrict__ embT) {
  __shared__ float tt[32][65];
  __shared__ unsigned long long sel_keys[4][KNB];   // per-wave topk scratch
  int blk = blockIdx.x;
  int tid = threadIdx.x;

  if (blk < 800) {            // ---- mean partials ----
    if (tid < 128) {
      int b = blk / MCHUNK;
      int chunk = blk % MCHUNK;
      const float* eb = emb + ((size_t)b * NN + chunk * MROWS) * HH;
      float acc = 0.f;
#pragma unroll
      for (int n = 0; n < MROWS; ++n) acc += eb[n * HH + tid];
      partial[(size_t)blk * HH + tid] = acc;
    }
    return;
  }
  if (blk < 816) {            // ---- Wsum ----
    if (tid < 128) {
      int idx = (blk - 800) * 128 + tid;
      const float4* f4 = (const float4*)Wqf;
      const float4* l4 = (const float4*)Wql;
      float4* s4 = (float4*)Wsum;
      for (int i = idx; i < (HH * HH) / 4; i += 2048) {
        float4 a = f4[i], c = l4[i];
        s4[i] = make_float4(a.x + c.x, a.y + c.y, a.z + c.z, a.w + c.w);
      }
    }
    return;
  }
  if (blk < 4816) {           // ---- topk: bit-pattern binary search ----
    // Positive-float bits are order-monotone as uints: find the 16th-smallest
    // value via 31-step binary search (8 ballots + SALU popcounts per step,
    // no cross-lane shuffles). Selection = {u < V} + first (16-cnt_less) of
    // {u == V} in index order (== jax top_k stable tie-break). 16-key LDS
    // rank-sort restores exact ascending-(distance,index) reference order.
    int lane = tid & 63;
    int wid = tid >> 6;
    int row = (blk - 816) * 4 + wid;
    if (row >= BB * GG) return;      // never taken (4000*4 == 16000), uniform
    int b = row / GG;
    int last = last_node[row];
    const float* cb = coords + (size_t)b * NN * 2;
    float lx = cb[(size_t)last * 2 + 0];
    float ly = cb[(size_t)last * 2 + 1];
    const float* mrow = mask + (size_t)row * NN;
    unsigned u[8];
#pragma unroll
    for (int j = 0; j < 8; ++j) {
      int n = lane + j * 64;
      unsigned uv = 0x7FFFFFFFu;               // pad slots: above +inf
      if (n < NN) {
        float dx = lx - cb[n * 2];
        float dy = ly - cb[n * 2 + 1];
        float d = sqrtf(dx * dx + dy * dy);
        uv = __float_as_uint(d);               // d >= 0: bits are monotone
        if (mrow[n] == -INFINITY) uv = 0x7F800000u;   // +inf
      }
      u[j] = uv;
    }
    // smallest V with #{u <= V} >= 16  (V16 <= +inf always: 500 valid slots)
    unsigned lo = 0u, hi = 0x7F800000u;
    for (int it = 0; it < 31; ++it) {
      unsigned mid = (lo + hi) >> 1;
      int cnt = 0;
#pragma unroll
      for (int j = 0; j < 8; ++j)
        cnt += __popcll(__ballot(u[j] <= mid));
      if (cnt >= KNB) hi = mid; else lo = mid + 1;
    }
    unsigned V = hi;
    int cnt_less = 0;
#pragma unroll
    for (int j = 0; j < 8; ++j)
      cnt_less += __popcll(__ballot(u[j] < V));
    int extra = KNB - cnt_less;                // >= 1 by minimality of V
    // scatter the 16 selected keys (u:31 | n:9) into per-wave LDS
    unsigned long long below = (1ull << lane) - 1ull;
    unsigned long long* skey = &sel_keys[wid][0];
    int base_lt = 0, base_eq = 0;
#pragma unroll
    for (int j = 0; j < 8; ++j) {
      unsigned long long ltb = __ballot(u[j] < V);
      unsigned long long eqb = __ballot(u[j] == V);
      int n = lane + j * 64;
      if (u[j] < V) {
        int pos = base_lt + __popcll(ltb & below);
        skey[pos] = ((unsigned long long)u[j] << 9) | (unsigned)n;
      } else if (u[j] == V) {
        int erk = base_eq + __popcll(eqb & below);
        if (erk < extra)
          skey[cnt_less + erk] = ((unsigned long long)u[j] << 9) | (unsigned)n;
      }
      base_lt += __popcll(ltb);
      base_eq += __popcll(eqb);
    }
    // rank-sort 16 keys (DS ops are in-order within a wave; no barrier needed)
    if (lane < KNB) {
      unsigned long long mykey = skey[lane];
      int rank = 0;
#pragma unroll
      for (int k = 0; k < KNB; ++k)
        rank += (skey[k] < mykey) ? 1 : 0;
      nbr[(size_t)row * KNB + rank] = (int)(mykey & 511ull);
    }
    return;
  }
  // ---- transpose: emb(B,N,H) -> embT(B,H,NPAD), pad n>=500 with 0 ----
  {
    int blkt = blk - 4816;            // 0..1023
    int b = blkt >> 5;
    int t32 = blkt & 31;
    int h0 = (t32 >> 3) * 32;         // 4 h-tiles of 32
    int n0 = (t32 & 7) * 64;          // 8 n-tiles of 64
    int r = tid >> 2;                 // 0..63 (n within tile)
    int c = tid & 3;                  // h-octet 0..3
    int n = n0 + r;
    float4 f0 = make_float4(0.f, 0.f, 0.f, 0.f), f1 = f0;
    if (n < NN) {
      const float* src = emb + ((size_t)b * NN + n) * HH + h0 + c * 8;
      f0 = *(const float4*)(src);
      f1 = *(const float4*)(src + 4);
    }
    tt[c * 8 + 0][r] = f0.x; tt[c * 8 + 1][r] = f0.y;
    tt[c * 8 + 2][r] = f0.z; tt[c * 8 + 3][r] = f0.w;
    tt[c * 8 + 4][r] = f1.x; tt[c * 8 + 5][r] = f1.y;
    tt[c * 8 + 6][r] = f1.z; tt[c * 8 + 7][r] = f1.w;
    __syncthreads();
    int hr = tid >> 3;                // 0..31
    int nc = tid & 7;                 // 0..7 (n-octet)
    float* dst = embT + ((size_t)b * HH + h0 + hr) * NPAD + n0 + nc * 8;
    *(float4*)(dst)     = make_float4(tt[hr][nc*8+0], tt[hr][nc*8+1],
                                      tt[hr][nc*8+2], tt[hr][nc*8+3]);
    *(float4*)(dst + 4) = make_float4(tt[hr][nc*8+4], tt[hr][nc*8+5],
                                      tt[hr][nc*8+6], tt[hr][nc*8+7]);
  }
}

// ---------------------------------------------------------------------------
// Kernel 1b: reduce partials -> mean, project through Wqg -> qgraph (B,H)
// ---------------------------------------------------------------------------
__global__ __launch_bounds__(128) void qgraph_kernel(
    const float* __restrict__ partial, const float* __restrict__ Wqg,
    float* __restrict__ qgraph) {
  int b = blockIdx.x;
  int tid = threadIdx.x;
  __shared__ float meanv[HH];
  const float* p = partial + (size_t)b * MCHUNK * HH;
  float acc = 0.f;
#pragma unroll
  for (int c = 0; c < MCHUNK; ++c) acc += p[c * HH + tid];
  meanv[tid] = acc * (1.0f / NN);
  __syncthreads();
  const float4* wrow = (const float4*)(Wqg + (size_t)tid * HH);
  float s = 0.f;
#pragma unroll
  for (int k = 0; k < HH / 4; ++k) {
    float4 w = wrow[k];
    s += meanv[4 * k] * w.x + meanv[4 * k + 1] * w.y +
         meanv[4 * k + 2] * w.z + meanv[4 * k + 3] * w.w;
  }
  qgraph[b * HH + tid] = s;
}

// ---------------------------------------------------------------------------
// R2-style projection body: A and W both LDS-staged, 4 rows x 4 cols / thread.
// ---------------------------------------------------------------------------
__device__ __forceinline__ void proj_body(
    const float* __restrict__ A, const int* __restrict__ gather,
    const float* __restrict__ W, const float* __restrict__ bias,
    float* __restrict__ out, int mode, int blk,
    float (*As)[36], float (*Ws)[132]) {
  int tid = threadIdx.x;
  int row0 = blk * 32;

  float acc[4][4];
#pragma unroll
  for (int i = 0; i < 4; ++i)
#pragma unroll
    for (int j = 0; j < 4; ++j) acc[i][j] = 0.f;

  int cg = tid & 31; int c0 = cg * 4;
  int rg = tid >> 5; int r0 = rg * 4;

  int sr = tid >> 3;
  int skq = tid & 7;
  int grow = row0 + sr;
  int arow;
  if (gather) {
    int bofr = grow / GG;
    arow = bofr * NN + gather[grow];
  } else {
    arow = grow;
  }
  const float4* Arow4 = (const float4*)(A + (size_t)arow * HH);

  for (int ks = 0; ks < 4; ++ks) {
    int k0 = ks * 32;
    float4 a4 = Arow4[(k0 >> 2) + skq];
    As[skq * 4 + 0][sr] = a4.x;
    As[skq * 4 + 1][sr] = a4.y;
    As[skq * 4 + 2][sr] = a4.z;
    As[skq * 4 + 3][sr] = a4.w;
#pragma unroll
    for (int j = 0; j < 4; ++j) {
      int f = tid + j * 256;
      int o = f >> 3; int kq = f & 7;
      float4 w4 = *(const float4*)(W + (size_t)o * HH + k0 + kq * 4);
      Ws[kq * 4 + 0][o] = w4.x;
      Ws[kq * 4 + 1][o] = w4.y;
      Ws[kq * 4 + 2][o] = w4.z;
      Ws[kq * 4 + 3][o] = w4.w;
    }
    __syncthreads();
#pragma unroll
    for (int k = 0; k < 32; ++k) {
      float4 av = *(const float4*)&As[k][r0];
      float4 wv = *(const float4*)&Ws[k][c0];
      acc[0][0] += av.x*wv.x; acc[0][1] += av.x*wv.y;
      acc[0][2] += av.x*wv.z; acc[0][3] += av.x*wv.w;
      acc[1][0] += av.y*wv.x; acc[1][1] += av.y*wv.y;
      acc[1][2] += av.y*wv.z; acc[1][3] += av.y*wv.w;
      acc[2][0] += av.z*wv.x; acc[2][1] += av.z*wv.y;
      acc[2][2] += av.z*wv.z; acc[2][3] += av.z*wv.w;
      acc[3][0] += av.w*wv.x; acc[3][1] += av.w*wv.y;
      acc[3][2] += av.w*wv.z; acc[3][3] += av.w*wv.w;
    }
    __syncthreads();
  }

#pragma unroll
  for (int i = 0; i < 4; ++i) {
    int orow = row0 + r0 + i;
    float b0 = 0.f, b1 = 0.f, b2 = 0.f, b3 = 0.f;
    if (mode == 1) {
      int bofr = orow / GG;
      const float* qg = bias + bofr * HH + c0;
      b0 = qg[0]; b1 = qg[1]; b2 = qg[2]; b3 = qg[3];
    } else if (mode == 2) {
      b0 = bias[c0 + 0]; b1 = bias[c0 + 1]; b2 = bias[c0 + 2]; b3 = bias[c0 + 3];
    }
    float4 o4;
    o4.x = acc[i][0] + b0; o4.y = acc[i][1] + b1;
    o4.z = acc[i][2] + b2; o4.w = acc[i][3] + b3;
    *(float4*)(out + (size_t)orow * HH + c0) = o4;
  }
}

// seg 0: Kb=emb@Wk ; seg 1: Vb=emb@Wv ; seg 2: Qb=gather(emb)@Wsum + qgraph
// seg 3: FQ=AO@Wc + bc   (launched separately after attn)
__global__ __launch_bounds__(256) void proj_kernel(
    const float* __restrict__ emb, const int* __restrict__ last_node,
    const float* __restrict__ Wk, const float* __restrict__ Wv,
    const float* __restrict__ Wsum, const float* __restrict__ qgraph,
    const float* __restrict__ Wc, const float* __restrict__ bc,
    const float* __restrict__ AO, float* __restrict__ Kb,
    float* __restrict__ Vb, float* __restrict__ Qb, float* __restrict__ FQ,
    int seg_base) {
  __shared__ float As[32][36];
  __shared__ float Ws[32][132];
  int seg = seg_base + blockIdx.x / 500;
  int blk = blockIdx.x % 500;
  if (seg == 0)      proj_body(emb, nullptr,   Wk,   nullptr, Kb, 0, blk, As, Ws);
  else if (seg == 1) proj_body(emb, nullptr,   Wv,   nullptr, Vb, 0, blk, As, Ws);
  else if (seg == 2) proj_body(emb, last_node, Wsum, qgraph,  Qb, 1, blk, As, Ws);
  else               proj_body(AO,  nullptr,   Wc,   bc,      FQ, 2, blk, As, Ws);
}

// ---------------------------------------------------------------------------
// Kernel 4: sparse glimpse attention — R14 config (best measured).
// Direct-accumulate PV: weights broadcast via 640 B LDS, output accumulated
// straight from global V rows (bit-identical AO; no vacc buffer/barrier).
// R15's XCD swizzle here was neutral (16000 blocks = ample TLP) -> linear.
// ---------------------------------------------------------------------------
__global__ __launch_bounds__(128) void attn_kernel(
    const float* __restrict__ Q, const float* __restrict__ Kb,
    const float* __restrict__ Vb, const int* __restrict__ nbr,
    float* __restrict__ AO) {
  int row = blockIdx.x;
  int b = row / GG;
  int t = threadIdx.x;
  __shared__ float qs[HH];
  __shared__ int nb[KNB];
  __shared__ float aw[NHEADS * KNB];    // attention weights [h][i]
  qs[t] = Q[(size_t)row * HH + t];
  if (t < KNB) nb[t] = nbr[(size_t)row * KNB + t];
  __syncthreads();
  int h = t >> 4;
  int i = t & 15;
  size_t nrow = (size_t)b * NN + nb[i];
  const float4* kr = (const float4*)(Kb + nrow * HH + h * DD);
  const float4* q4 = (const float4*)(qs + h * DD);
  float4 k0 = kr[0], k1 = kr[1], k2 = kr[2], k3 = kr[3];
  float4 qa = q4[0], qb = q4[1], qc = q4[2], qd = q4[3];
  float s = k0.x*qa.x + k0.y*qa.y + k0.z*qa.z + k0.w*qa.w
          + k1.x*qb.x + k1.y*qb.y + k1.z*qb.z + k1.w*qb.w
          + k2.x*qc.x + k2.y*qc.y + k2.z*qc.z + k2.w*qc.w
          + k3.x*qd.x + k3.y*qd.y + k3.z*qd.z + k3.w*qd.w;
  s *= 0.25f;
  float m = s;
#pragma unroll
  for (int off = 8; off; off >>= 1) m = fmaxf(m, __shfl_xor(m, off, 64));
  float e = __expf(s - m);
  float sum = e;
#pragma unroll
  for (int off = 8; off; off >>= 1) sum += __shfl_xor(sum, off, 64);
  aw[h * KNB + i] = e / sum;
  __syncthreads();

  const float* awh = &aw[h * KNB];      // this thread's head weights
  const float* vb = Vb + (size_t)b * NN * HH + t;
  float o = 0.f;
#pragma unroll
  for (int k = 0; k < KNB; ++k)
    o += awh[k] * vb[(size_t)nb[k] * HH];
  AO[(size_t)row * HH + t] = o;
}

// ---------------------------------------------------------------------------
// Kernel 5: pointer scores — R11 config (best measured: 42-46 us, FETCH
// 28 MB, VGPR 52, zero spill). XCD-affine swizzle (embT L2-resident per
// XCD) + register double-buffer prefetch (covers ~200cy L2-hit latency with
// 512cy of FMA). Declared structurally floored in this decomposition (R12
// PGT=16 and R13 256-thr h-split both regressed via wave-supply / spill).
// tanh(x)*10 - 10 = -20/(exp(2x)+1); no max reduction needed.
// ---------------------------------------------------------------------------
__global__ __launch_bounds__(128) void pointer_kernel(
    const float* __restrict__ FQ, const float* __restrict__ embT,
    const float* __restrict__ mask, float* __restrict__ out) {
  int hb = blockIdx.x;                  // 0..2015
  int xcd = hb & 7;                     // presumed XCD (round-robin dispatch)
  int slot = hb >> 3;                   // 0..251 within this XCD
  int b = xcd * 4 + slot / PTILES;      // 4 b-slices per XCD (252 = 4*63)
  int g0 = (slot % PTILES) * PGT;
  int gc = min(PGT, GG - g0);
  int tid = threadIdx.x;

  const float* fq = FQ + (size_t)(b * GG + g0) * HH;   // block-uniform base
  const float4* et = (const float4*)(embT + (size_t)b * HH * NPAD);
  const float4* pe = et + tid;          // row h at pe[h*128]

  float4 acc[PGT];
#pragma unroll
  for (int g = 0; g < PGT; ++g) acc[g] = make_float4(0.f, 0.f, 0.f, 0.f);

  // prologue: rows 0..3 in flight
  float4 a0 = pe[0];
  float4 a1 = pe[128];
  float4 a2 = pe[256];
  float4 a3 = pe[384];
  pe += 512;

#define PTR_FMA_BLOCK(hh)                                          \
  do {                                                             \
    _Pragma("unroll")                                              \
    for (int g = 0; g < PGT; ++g) {                                \
      float4 w = *(const float4*)(fq + g * HH + (hh));             \
      acc[g].x = fmaf(a0.x, w.x, acc[g].x);                        \
      acc[g].x = fmaf(a1.x, w.y, acc[g].x);                        \
      acc[g].x = fmaf(a2.x, w.z, acc[g].x);                        \
      acc[g].x = fmaf(a3.x, w.w, acc[g].x);                        \
      acc[g].y = fmaf(a0.y, w.x, acc[g].y);                        \
      acc[g].y = fmaf(a1.y, w.y, acc[g].y);                        \
      acc[g].y = fmaf(a2.y, w.z, acc[g].y);                        \
      acc[g].y = fmaf(a3.y, w.w, acc[g].y);                        \
      acc[g].z = fmaf(a0.z, w.x, acc[g].z);                        \
      acc[g].z = fmaf(a1.z, w.y, acc[g].z);                        \
      acc[g].z = fmaf(a2.z, w.z, acc[g].z);                        \
      acc[g].z = fmaf(a3.z, w.w, acc[g].z);                        \
      acc[g].w = fmaf(a0.w, w.x, acc[g].w);                        \
      acc[g].w = fmaf(a1.w, w.y, acc[g].w);                        \
      acc[g].w = fmaf(a2.w, w.z, acc[g].w);                        \
      acc[g].w = fmaf(a3.w, w.w, acc[g].w);                        \
    }                                                              \
  } while (0)

#pragma unroll 2
  for (int h4 = 0; h4 < 31; ++h4) {
    // prefetch next 4 rows before this iteration's FMAs (256cy cover)
    float4 b0 = pe[0];
    float4 b1 = pe[128];
    float4 b2 = pe[256];
    float4 b3 = pe[384];
    pe += 512;
    PTR_FMA_BLOCK(h4 * 4);
    a0 = b0; a1 = b1; a2 = b2; a3 = b3;
  }
  PTR_FMA_BLOCK(124);                   // peeled final iteration
#undef PTR_FMA_BLOCK

  // epilogue: tanh-clip + mask + exp (in place), block-sum per g, normalize
  __shared__ float wred[2][PGT];
  __shared__ float tot[PGT];
  int lane = tid & 63;
  int w = tid >> 6;
  bool valid = (tid < 125);             // n = 4*tid < 500

#pragma unroll
  for (int g = 0; g < PGT; ++g) {
    float4 p = make_float4(0.f, 0.f, 0.f, 0.f);
    if (g < gc && valid) {
      const float* mrow = mask + (size_t)(b * GG + g0 + g) * NN;
      float4 m4 = *(const float4*)(mrow + 4 * tid);
      p.x = __expf(-20.f / (__expf(2.f * acc[g].x) + 1.f) + m4.x);
      p.y = __expf(-20.f / (__expf(2.f * acc[g].y) + 1.f) + m4.y);
      p.z = __expf(-20.f / (__expf(2.f * acc[g].z) + 1.f) + m4.z);
      p.w = __expf(-20.f / (__expf(2.f * acc[g].w) + 1.f) + m4.w);
    }
    acc[g] = p;
    float s = p.x + p.y + p.z + p.w;
#pragma unroll
    for (int off = 32; off; off >>= 1) s += __shfl_xor(s, off, 64);
    if (lane == 0) wred[w][g] = s;
  }
  __syncthreads();
  if (tid < PGT) tot[tid] = wred[0][tid] + wred[1][tid];
  __syncthreads();

#pragma unroll
  for (int g = 0; g < PGT; ++g) {
    if (g < gc && valid) {
      float inv = 1.f / tot[g];
      float4 p = acc[g];
      float4 o4 = make_float4(p.x * inv, p.y * inv, p.z * inv, p.w * inv);
      *(float4*)(out + (size_t)(b * GG + g0 + g) * NN + 4 * tid) = o4;
    }
  }
}

// ---------------------------------------------------------------------------
extern "C" void kernel_launch(void* const* d_in, const int* in_sizes, int n_in,
                              void* d_out, int out_size, void* d_ws,
                              size_t ws_size, hipStream_t stream) {
  const float* coords    = (const float*)d_in[0];
  const float* emb       = (const float*)d_in[1];
  const int*   last_node = (const int*)d_in[2];
  const float* mask      = (const float*)d_in[3];
  const float* Wqg       = (const float*)d_in[4];
  const float* Wqf       = (const float*)d_in[5];
  const float* Wql       = (const float*)d_in[6];
  const float* Wk        = (const float*)d_in[7];
  const float* Wv        = (const float*)d_in[8];
  const float* Wc        = (const float*)d_in[9];
  const float* bc        = (const float*)d_in[10];

  float* wsf    = (float*)d_ws;
  float* Wsum   = wsf;                            // 16 K floats
  float* qgraph = Wsum + HH * HH;                 // 4 K
  float* Kb     = qgraph + BB * HH;               // 2.048 M
  float* Vb     = Kb + (size_t)BB * NN * HH;      // 2.048 M
  float* Qb     = Vb + (size_t)BB * NN * HH;      // 2.048 M (reused for FQ)
  float* AO     = Qb + (size_t)BB * GG * HH;      // 2.048 M
  int*   nbr    = (int*)(AO + (size_t)BB * GG * HH);      // 256 K ints
  float* partial = (float*)(nbr + (size_t)BB * GG * KNB); // 102 K
  float* embT   = partial + (size_t)BB * MCHUNK * HH;     // 2.097 M

  float* outp   = (float*)d_out;

  combo1_kernel<<<5840, 256, 0, stream>>>(emb, Wqf, Wql, coords, last_node,
                                          mask, partial, Wsum, nbr, embT);
  qgraph_kernel<<<BB, 128, 0, stream>>>(partial, Wqg, qgraph);
  proj_kernel<<<1500, 256, 0, stream>>>(emb, last_node, Wk, Wv, Wsum, qgraph,
                                        Wc, bc, AO, Kb, Vb, Qb, Qb, 0);
  attn_kernel<<<BB * GG, 128, 0, stream>>>(Qb, Kb, Vb, nbr, AO);
  proj_kernel<<<500, 256, 0, stream>>>(emb, last_node, Wk, Wv, Wsum, qgraph,
                                       Wc, bc, AO, Kb, Vb, Qb, Qb, 3);
  pointer_kernel<<<BB * PTILES, 128, 0, stream>>>(Qb, embT, mask, outp);
}